// Round 2
// baseline (714.847 us; speedup 1.0000x reference)
//
#include <hip/hip_runtime.h>
#include <cstdint>

// Problem constants (fixed by setup_inputs: B=16, N_OBJ=16, C*W*H=25088, fp32)
#define NIMG          16
#define NOBJ          16
#define PAIRS_PER_IMG 120   // n(n-1)/2
#define ROWS_PER_IMG  136   // n(n+1)/2
#define ROW_ELEMS     25088 // 512*7*7 float32 elements
#define CHUNKS        6272  // ROW_ELEMS * 4 bytes / 16 bytes per uint4
#define OUT_ROWS      (NIMG * PAIRS_PER_IMG * 3)  // 5760

__global__ __launch_bounds__(256) void obj_pair_gather(
    const uint4* __restrict__ src, uint4* __restrict__ dst)
{
    const int row = blockIdx.x;            // 0..5759 output row
    const int k   = row % 3;               // which of the pair-triple
    const int p   = row / 3;               // global pair index
    const int b   = p / PAIRS_PER_IMG;     // image
    const int q   = p - b * PAIRS_PER_IMG; // local pair index / union counter

    int srcRow;
    if (k == 2) {
        srcRow = b * ROWS_PER_IMG + NOBJ + q;          // union feat
    } else {
        // decode row-major triu pair (o1,o2), o1<o2, from q
        int o1 = 0, rem = q, cnt = NOBJ - 1;
        while (rem >= cnt) { rem -= cnt; --cnt; ++o1; }
        const int o2 = o1 + 1 + rem;
        srcRow = b * ROWS_PER_IMG + (k == 0 ? o1 : o2); // single feats
    }

    const uint4* __restrict__ s = src + (size_t)srcRow * CHUNKS;
    uint4* __restrict__ d       = dst + (size_t)row    * CHUNKS;

    // 6272 chunks / 256 threads = 24.5 iterations, fully coalesced 16B/lane
    for (int i = threadIdx.x; i < CHUNKS; i += 256) {
        d[i] = s[i];
    }
}

extern "C" void kernel_launch(void* const* d_in, const int* in_sizes, int n_in,
                              void* d_out, int out_size, void* d_ws, size_t ws_size,
                              hipStream_t stream) {
    const uint4* src = (const uint4*)d_in[0];  // fp32 [2176, 25088] viewed as uint4
    uint4* dst       = (uint4*)d_out;          // fp32 [1920, 3, 25088] viewed as uint4
    obj_pair_gather<<<OUT_ROWS, 256, 0, stream>>>(src, dst);
}